// Round 7
// baseline (608.636 us; speedup 1.0000x reference)
//
#include <hip/hip_runtime.h>
#include <hip/hip_fp16.h>

#define NN 100000
#define NE 1200000
#define DIM 64
#define NBINS 391                 // bin = dst >> 8  (256 nodes per bin)
#define NBE 128                   // edge-partition blocks
#define CHUNK (NE / NBE)          // 9375, exact
#define NBLK ((NN + 255) / 256)   // 391 scan blocks
#define NPH 7                     // src phases, phase = src >> 14

// out = sc[d]*y + bx[d] + sum_e w_e * Y[src_e]
//   sc = 0.5625 - 0.5*rD ; bx = 0.5*rD*x
//   g0 edge: w = (0.5*inv0[dst]) * rsqrt(deg0[src])
//   g1 edge: w = (-0.0625*inv1[dst]) * rsqrt(deg1[src])
// edge record (4B): [deg:7|g:1|src:17]

__global__ void __launch_bounds__(256) bin_count(const int* __restrict__ dst0,
                                                 const int* __restrict__ dst1,
                                                 int* __restrict__ blk_cnt) {
    __shared__ int c[NBINS];
    int t = threadIdx.x;
    for (int i = t; i < NBINS; i += 256) c[i] = 0;
    __syncthreads();
    int lo = blockIdx.x * CHUNK, hi = lo + CHUNK;
    for (int e = lo + t; e < hi; e += 256) {
        atomicAdd(&c[dst0[e] >> 8], 1);
        atomicAdd(&c[dst1[e] >> 8], 1);
    }
    __syncthreads();
    for (int i = t; i < NBINS; i += 256) blk_cnt[blockIdx.x * NBINS + i] = c[i];
}

__global__ void __launch_bounds__(512) bin_scan(const int* __restrict__ blk_cnt,
                                                int* __restrict__ bin_start) {
    __shared__ int tot[512];
    int t = threadIdx.x;
    int s = 0;
    if (t < NBINS)
        for (int b = 0; b < NBE; ++b) s += blk_cnt[b * NBINS + t];
    tot[t] = s;
    __syncthreads();
    for (int off = 1; off < 512; off <<= 1) {
        int v = (t >= off) ? tot[t - off] : 0;
        __syncthreads();
        tot[t] += v;
        __syncthreads();
    }
    if (t <= NBINS) bin_start[t] = tot[t] - s;
}

__global__ void __launch_bounds__(NBE) blk_base_k(const int* __restrict__ blk_cnt,
                                                  const int* __restrict__ bin_start,
                                                  int* __restrict__ blk_base) {
    __shared__ int s[NBE];
    int b = blockIdx.x, t = threadIdx.x;
    int v = blk_cnt[t * NBINS + b];
    s[t] = v;
    __syncthreads();
    for (int off = 1; off < NBE; off <<= 1) {
        int x = (t >= off) ? s[t - off] : 0;
        __syncthreads();
        s[t] += x;
        __syncthreads();
    }
    blk_base[t * NBINS + b] = bin_start[b] + s[t] - v;
}

__global__ void __launch_bounds__(256) bin_permute(const int* __restrict__ src0,
                                                   const int* __restrict__ dst0,
                                                   const int* __restrict__ src1,
                                                   const int* __restrict__ dst1,
                                                   const int* __restrict__ blk_base,
                                                   int2* __restrict__ binned) {
    __shared__ int off[NBINS];
    int t = threadIdx.x;
    for (int i = t; i < NBINS; i += 256) off[i] = blk_base[blockIdx.x * NBINS + i];
    __syncthreads();
    int lo = blockIdx.x * CHUNK, hi = lo + CHUNK;
    for (int e = lo + t; e < hi; e += 256) {
        int s = src0[e], d = dst0[e];
        int p = atomicAdd(&off[d >> 8], 1);
        binned[p] = make_int2(s, d);
        s = src1[e]; d = dst1[e];
        p = atomicAdd(&off[d >> 8], 1);
        binned[p] = make_int2(s, d | (1 << 20));
    }
}

__global__ void __launch_bounds__(256) deg_count(const int2* __restrict__ binned,
                                                 const int* __restrict__ bin_start,
                                                 int* __restrict__ deg0,
                                                 int* __restrict__ deg1) {
    __shared__ int dg[512];
    int b = blockIdx.x, t = threadIdx.x;
    dg[t] = 0; dg[t + 256] = 0;
    __syncthreads();
    int lo = bin_start[b], hi = bin_start[b + 1];
    for (int i = lo + t; i < hi; i += 256) {
        int2 r = binned[i];
        int d = r.y & 0xFFFFF, g = r.y >> 20;
        atomicAdd(&dg[((d & 255) << 1) | g], 1);
    }
    __syncthreads();
    int n = b * 256 + t;
    if (n < NN) { deg0[n] = dg[t << 1]; deg1[n] = dg[(t << 1) | 1]; }
}

__global__ void __launch_bounds__(256) scan_l1(const int* __restrict__ deg0,
                                               const int* __restrict__ deg1,
                                               int* __restrict__ rs, int* __restrict__ dp,
                                               int* __restrict__ bs) {
    __shared__ int s0[256];
    int t = threadIdx.x;
    int n = blockIdx.x * 256 + t;
    int a = 0;
    if (n < NN) a = (deg0[n] + deg1[n] + 7) & ~7;
    s0[t] = a;
    __syncthreads();
    for (int off = 1; off < 256; off <<= 1) {
        int x0 = (t >= off) ? s0[t - off] : 0;
        __syncthreads();
        s0[t] += x0;
        __syncthreads();
    }
    if (n < NN) { rs[n] = s0[t] - a; dp[n] = a; }
    if (t == 255) bs[blockIdx.x] = s0[255];
}

__global__ void __launch_bounds__(512) scan_l2(int* __restrict__ bs) {
    __shared__ int s0[512];
    int t = threadIdx.x;
    int a = (t < NBLK) ? bs[t] : 0;
    s0[t] = a;
    __syncthreads();
    for (int off = 1; off < 512; off <<= 1) {
        int x0 = (t >= off) ? s0[t - off] : 0;
        __syncthreads();
        s0[t] += x0;
        __syncthreads();
    }
    if (t < NBLK) bs[t] = s0[t] - a;
}

__global__ void __launch_bounds__(256) scan_l3(int* __restrict__ rs, const int* __restrict__ bs) {
    int n = blockIdx.x * 256 + threadIdx.x;
    if (n < NN) rs[n] += bs[blockIdx.x];
}

__global__ void node_params(const int* __restrict__ deg0, const int* __restrict__ deg1,
                            float2* __restrict__ nsc, float* __restrict__ sc,
                            float* __restrict__ cy) {
    int n = blockIdx.x * blockDim.x + threadIdx.x;
    if (n < NN) {
        int a = deg0[n], b = deg1[n];
        nsc[n] = make_float2((a > 0) ? 0.5f * rsqrtf((float)a) : 0.0f,
                             (b > 0) ? -0.0625f * rsqrtf((float)b) : 0.0f);
        int s = a + b;
        float rD = (s > 0) ? 1.0f / (float)s : 0.0f;
        sc[n] = 0.5625f - 0.5f * rD;
        cy[n] = 0.5f * rD;
    }
}

// Pad slots [degsum, dp) -> 0 == {src=0, g=0, deg=0}; lut[0]=0 makes them no-ops.
__global__ void pad_fill(const int* __restrict__ deg0, const int* __restrict__ deg1,
                         const int* __restrict__ dp, const int* __restrict__ rs,
                         int* __restrict__ es) {
    int n = blockIdx.x * blockDim.x + threadIdx.x;
    if (n < NN) {
        int b = rs[n] + deg0[n] + deg1[n], e = rs[n] + dp[n];
        for (int i = b; i < e; ++i) es[i] = 0;
    }
}

// One block per bin; NPH predicated sweeps => each node's list is src-phase
// sorted (all waves later sweep src-space in ~2MB windows => L2-local gathers).
__global__ void __launch_bounds__(256) csr_scatter(const int2* __restrict__ binned,
                                                   const int* __restrict__ bin_start,
                                                   const int* __restrict__ rs,
                                                   const int* __restrict__ deg0,
                                                   const int* __restrict__ deg1,
                                                   int* __restrict__ es) {
    __shared__ int cur[256];
    int b = blockIdx.x, t = threadIdx.x;
    cur[t] = 0;
    __syncthreads();
    int lo = bin_start[b], hi = bin_start[b + 1];
    for (int ph = 0; ph < NPH; ++ph) {
        for (int i = lo + t; i < hi; i += 256) {
            int2 r = binned[i];
            int sN = r.x;
            if ((sN >> 14) != ph) continue;
            int d = r.y & 0xFFFFF, g = r.y >> 20;
            int dg = g ? deg1[sN] : deg0[sN];
            int p = atomicAdd(&cur[d & 255], 1);
            es[rs[d] + p] = sN | (g << 17) | (dg << 18);
        }
        __syncthreads();
    }
}

// HA = fp16(x); BX = fp16(0.5*rD*x)
__global__ void convert_x(const float* __restrict__ X, const float* __restrict__ cy,
                          __half* __restrict__ HA, __half* __restrict__ BX) {
    int i = blockIdx.x * blockDim.x + threadIdx.x;
    if (i < NN * DIM / 4) {
        float4 v = ((const float4*)X)[i];
        float c = cy[i >> 4];
        ushort4 a, b;
        a.x = __half_as_ushort(__float2half(v.x));
        a.y = __half_as_ushort(__float2half(v.y));
        a.z = __half_as_ushort(__float2half(v.z));
        a.w = __half_as_ushort(__float2half(v.w));
        b.x = __half_as_ushort(__float2half(v.x * c));
        b.y = __half_as_ushort(__float2half(v.y * c));
        b.z = __half_as_ushort(__float2half(v.z * c));
        b.w = __half_as_ushort(__float2half(v.w * c));
        ((ushort4*)HA)[i] = a;
        ((ushort4*)BX)[i] = b;
    }
}

// One wave per node; fp16 state; packed 4B edge records; LDS rsqrt LUT.
__global__ void __launch_bounds__(256) step_kernel(
    const __half* __restrict__ Yh, const __half* __restrict__ BX,
    const int* __restrict__ rs, const int* __restrict__ dp,
    const int* __restrict__ es, const float2* __restrict__ nsc,
    const float* __restrict__ sc,
    __half* __restrict__ Yho, float* __restrict__ Ffo)
{
    __shared__ float lut[128];
    for (int i = threadIdx.x; i < 128; i += 256)
        lut[i] = (i == 0) ? 0.0f : rsqrtf((float)i);
    __syncthreads();

    int node = blockIdx.x * 4 + (threadIdx.x >> 6);  // NN % 4 == 0
    int d = threadIdx.x & 63;
    int un = __builtin_amdgcn_readfirstlane(node);
    int s  = __builtin_amdgcn_readfirstlane(rs[un]);
    int c  = __builtin_amdgcn_readfirstlane(dp[un]);
    float2 ns = nsc[un];

    float acc = 0.0f;
    int eb[8];
#pragma unroll
    for (int k = 0; k < 8; ++k) eb[k] = es[s + k];
    for (int i = 0; i < c; i += 8) {
        int en[8];
#pragma unroll
        for (int k = 0; k < 8; ++k) en[k] = es[s + i + 8 + k];  // slack-padded prefetch
        float yv[8];
#pragma unroll
        for (int k = 0; k < 8; ++k)
            yv[k] = __half2float(Yh[(size_t)(eb[k] & 0x1FFFF) * DIM + d]);
#pragma unroll
        for (int k = 0; k < 8; ++k) {
            float wsc = (eb[k] & (1 << 17)) ? ns.y : ns.x;
            acc = fmaf(yv[k], wsc * lut[eb[k] >> 18], acc);
        }
#pragma unroll
        for (int k = 0; k < 8; ++k) eb[k] = en[k];
    }
    float y  = __half2float(Yh[(size_t)un * DIM + d]);
    float bx = __half2float(BX[(size_t)un * DIM + d]);
    float o = fmaf(sc[un], y, bx) + acc;
    if (Ffo) Ffo[(size_t)un * DIM + d] = o;         // final step: f32 output
    else     Yho[(size_t)un * DIM + d] = __float2half(o);
}

extern "C" void kernel_launch(void* const* d_in, const int* in_sizes, int n_in,
                              void* d_out, int out_size, void* d_ws, size_t ws_size,
                              hipStream_t stream) {
    const float* x   = (const float*)d_in[0];
    const int* src0  = (const int*)d_in[1];
    const int* dst0  = (const int*)d_in[2];
    const int* src1  = (const int*)d_in[3];
    const int* dst1  = (const int*)d_in[4];
    float* out = (float*)d_out;

    char* ws = (char*)d_ws;
    size_t off = 0;
    auto alloc = [&](size_t bytes) -> void* {
        void* p = ws + off;
        off += (bytes + 255) & ~(size_t)255;
        return p;
    };

    const size_t ES_CAP = (size_t)2 * NE + 8 * NN + 64;  // padded CSR + prefetch slack

    __half* HA   = (__half*)alloc((size_t)NN * DIM * 2);
    __half* HB   = (__half*)alloc((size_t)NN * DIM * 2);
    __half* BX   = (__half*)alloc((size_t)NN * DIM * 2);
    int2*   binned = (int2*)alloc((size_t)2 * NE * 8);
    int*    es   = (int*)alloc(ES_CAP * 4);
    int*    blk_cnt  = (int*)alloc((size_t)NBE * NBINS * 4);
    int*    blk_base = (int*)alloc((size_t)NBE * NBINS * 4);
    int*    bin_st   = (int*)alloc((size_t)(NBINS + 1) * 4);
    int*    deg0 = (int*)alloc((size_t)NN * 4);
    int*    deg1 = (int*)alloc((size_t)NN * 4);
    int*    rs   = (int*)alloc((size_t)NN * 4);
    int*    dp   = (int*)alloc((size_t)NN * 4);
    float2* nsc  = (float2*)alloc((size_t)NN * 8);
    float*  sc   = (float*)alloc((size_t)NN * 4);
    float*  cy   = (float*)alloc((size_t)NN * 4);
    int*    bs   = (int*)alloc((size_t)NBLK * 4);

    const int TB = 256;
    bin_count<<<NBE, 256, 0, stream>>>(dst0, dst1, blk_cnt);
    bin_scan<<<1, 512, 0, stream>>>(blk_cnt, bin_st);
    blk_base_k<<<NBINS, NBE, 0, stream>>>(blk_cnt, bin_st, blk_base);
    bin_permute<<<NBE, 256, 0, stream>>>(src0, dst0, src1, dst1, blk_base, binned);
    deg_count<<<NBINS, 256, 0, stream>>>(binned, bin_st, deg0, deg1);
    scan_l1<<<NBLK, 256, 0, stream>>>(deg0, deg1, rs, dp, bs);
    scan_l2<<<1, 512, 0, stream>>>(bs);
    scan_l3<<<NBLK, 256, 0, stream>>>(rs, bs);
    node_params<<<(NN + TB - 1) / TB, TB, 0, stream>>>(deg0, deg1, nsc, sc, cy);
    pad_fill<<<(NN + TB - 1) / TB, TB, 0, stream>>>(deg0, deg1, dp, rs, es);
    csr_scatter<<<NBINS, 256, 0, stream>>>(binned, bin_st, rs, deg0, deg1, es);
    convert_x<<<(NN * DIM / 4 + TB - 1) / TB, TB, 0, stream>>>(x, cy, HA, BX);

    int grid = NN / 4;
    for (int i = 0; i < 8; ++i) {
        const __half* hin = (i & 1) ? HB : HA;
        __half* hout = (i & 1) ? HA : HB;
        float* fout = (i == 7) ? out : nullptr;
        step_kernel<<<grid, TB, 0, stream>>>(hin, BX, rs, dp, es, nsc, sc, hout, fout);
    }
}

// Round 8
// 534.719 us; speedup vs baseline: 1.1382x; 1.1382x over previous
//
#include <hip/hip_runtime.h>
#include <hip/hip_fp16.h>

#define NN 100000
#define NE 1200000
#define DIM 64
#define NBINS 391                 // bin = dst >> 8  (256 nodes per bin)
#define NBE 128                   // edge-partition blocks
#define CHUNK (NE / NBE)          // 9375, exact
#define NBLK ((NN + 255) / 256)   // 391 scan blocks
#define NPH 7                     // src phases, phase = src >> 14

// out = sc[d]*y + bx[d] + sum_e w_e * Y[src_e]
//   sc = 0.5625 - 0.5*rD ; bx = 0.5*rD*x
//   g0 edge: w = (0.5*inv0[dst]) * rsqrt(deg0[src])
//   g1 edge: w = (-0.0625*inv1[dst]) * rsqrt(deg1[src])
// binned record (4B): [dstLow:8|g:1|src:17]   (dst = bin*256 + dstLow)
// es edge record (4B): [deg:7|g:1|src:17]

__global__ void __launch_bounds__(256) bin_count(const int* __restrict__ dst0,
                                                 const int* __restrict__ dst1,
                                                 int* __restrict__ blk_cnt) {
    __shared__ int c[NBINS];
    int t = threadIdx.x;
    for (int i = t; i < NBINS; i += 256) c[i] = 0;
    __syncthreads();
    int lo = blockIdx.x * CHUNK, hi = lo + CHUNK;
    for (int e = lo + t; e < hi; e += 256) {
        atomicAdd(&c[dst0[e] >> 8], 1);
        atomicAdd(&c[dst1[e] >> 8], 1);
    }
    __syncthreads();
    for (int i = t; i < NBINS; i += 256) blk_cnt[blockIdx.x * NBINS + i] = c[i];
}

__global__ void __launch_bounds__(512) bin_scan(const int* __restrict__ blk_cnt,
                                                int* __restrict__ bin_start) {
    __shared__ int tot[512];
    int t = threadIdx.x;
    int s = 0;
    if (t < NBINS)
        for (int b = 0; b < NBE; ++b) s += blk_cnt[b * NBINS + t];
    tot[t] = s;
    __syncthreads();
    for (int off = 1; off < 512; off <<= 1) {
        int v = (t >= off) ? tot[t - off] : 0;
        __syncthreads();
        tot[t] += v;
        __syncthreads();
    }
    if (t <= NBINS) bin_start[t] = tot[t] - s;
}

__global__ void __launch_bounds__(NBE) blk_base_k(const int* __restrict__ blk_cnt,
                                                  const int* __restrict__ bin_start,
                                                  int* __restrict__ blk_base) {
    __shared__ int s[NBE];
    int b = blockIdx.x, t = threadIdx.x;
    int v = blk_cnt[t * NBINS + b];
    s[t] = v;
    __syncthreads();
    for (int off = 1; off < NBE; off <<= 1) {
        int x = (t >= off) ? s[t - off] : 0;
        __syncthreads();
        s[t] += x;
        __syncthreads();
    }
    blk_base[t * NBINS + b] = bin_start[b] + s[t] - v;
}

__global__ void __launch_bounds__(256) bin_permute(const int* __restrict__ src0,
                                                   const int* __restrict__ dst0,
                                                   const int* __restrict__ src1,
                                                   const int* __restrict__ dst1,
                                                   const int* __restrict__ blk_base,
                                                   unsigned int* __restrict__ binned) {
    __shared__ int off[NBINS];
    int t = threadIdx.x;
    for (int i = t; i < NBINS; i += 256) off[i] = blk_base[blockIdx.x * NBINS + i];
    __syncthreads();
    int lo = blockIdx.x * CHUNK, hi = lo + CHUNK;
    for (int e = lo + t; e < hi; e += 256) {
        int s = src0[e], d = dst0[e];
        int p = atomicAdd(&off[d >> 8], 1);
        binned[p] = (unsigned)s | ((unsigned)(d & 255) << 18);
        s = src1[e]; d = dst1[e];
        p = atomicAdd(&off[d >> 8], 1);
        binned[p] = (unsigned)s | (1u << 17) | ((unsigned)(d & 255) << 18);
    }
}

__global__ void __launch_bounds__(256) deg_count(const unsigned int* __restrict__ binned,
                                                 const int* __restrict__ bin_start,
                                                 int* __restrict__ deg0,
                                                 int* __restrict__ deg1) {
    __shared__ int dg[512];
    int b = blockIdx.x, t = threadIdx.x;
    dg[t] = 0; dg[t + 256] = 0;
    __syncthreads();
    int lo = bin_start[b], hi = bin_start[b + 1];
    for (int i = lo + t; i < hi; i += 256) {
        unsigned r = binned[i];
        int dlow = (r >> 18) & 255, g = (r >> 17) & 1;
        atomicAdd(&dg[(dlow << 1) | g], 1);
    }
    __syncthreads();
    int n = b * 256 + t;
    if (n < NN) { deg0[n] = dg[t << 1]; deg1[n] = dg[(t << 1) | 1]; }
}

__global__ void __launch_bounds__(256) scan_l1(const int* __restrict__ deg0,
                                               const int* __restrict__ deg1,
                                               int* __restrict__ rs, int* __restrict__ dp,
                                               int* __restrict__ bs) {
    __shared__ int s0[256];
    int t = threadIdx.x;
    int n = blockIdx.x * 256 + t;
    int a = 0;
    if (n < NN) a = (deg0[n] + deg1[n] + 7) & ~7;
    s0[t] = a;
    __syncthreads();
    for (int off = 1; off < 256; off <<= 1) {
        int x0 = (t >= off) ? s0[t - off] : 0;
        __syncthreads();
        s0[t] += x0;
        __syncthreads();
    }
    if (n < NN) { rs[n] = s0[t] - a; dp[n] = a; }
    if (t == 255) bs[blockIdx.x] = s0[255];
}

__global__ void __launch_bounds__(512) scan_l2(int* __restrict__ bs) {
    __shared__ int s0[512];
    int t = threadIdx.x;
    int a = (t < NBLK) ? bs[t] : 0;
    s0[t] = a;
    __syncthreads();
    for (int off = 1; off < 512; off <<= 1) {
        int x0 = (t >= off) ? s0[t - off] : 0;
        __syncthreads();
        s0[t] += x0;
        __syncthreads();
    }
    if (t < NBLK) bs[t] = s0[t] - a;
}

__global__ void __launch_bounds__(256) scan_l3(int* __restrict__ rs, const int* __restrict__ bs) {
    int n = blockIdx.x * 256 + threadIdx.x;
    if (n < NN) rs[n] += bs[blockIdx.x];
}

__global__ void node_params(const int* __restrict__ deg0, const int* __restrict__ deg1,
                            float2* __restrict__ nsc, float* __restrict__ sc,
                            float* __restrict__ cy) {
    int n = blockIdx.x * blockDim.x + threadIdx.x;
    if (n < NN) {
        int a = deg0[n], b = deg1[n];
        nsc[n] = make_float2((a > 0) ? 0.5f * rsqrtf((float)a) : 0.0f,
                             (b > 0) ? -0.0625f * rsqrtf((float)b) : 0.0f);
        int s = a + b;
        float rD = (s > 0) ? 1.0f / (float)s : 0.0f;
        sc[n] = 0.5625f - 0.5f * rD;
        cy[n] = 0.5f * rD;
    }
}

// One block per bin, 2 passes: LDS (phase,node) histogram -> per-node scan
// -> phase-sorted scatter. Pad-fill folded in (degsum is in LDS).
__global__ void __launch_bounds__(256) csr_scatter(const unsigned int* __restrict__ binned,
                                                   const int* __restrict__ bin_start,
                                                   const int* __restrict__ rs,
                                                   const int* __restrict__ deg0,
                                                   const int* __restrict__ deg1,
                                                   int* __restrict__ es) {
    __shared__ int hist[8 * 256];   // [phase][node] counts, then cursors
    __shared__ int rsl[256];
    __shared__ int degsum[256];
    int b = blockIdx.x, t = threadIdx.x;
    int n = b * 256 + t;
    rsl[t] = (n < NN) ? rs[n] : 0;
    for (int i = t; i < 8 * 256; i += 256) hist[i] = 0;
    __syncthreads();
    int lo = bin_start[b], hi = bin_start[b + 1];
    for (int i = lo + t; i < hi; i += 256) {
        unsigned r = binned[i];
        int ph = (r & 0x1FFFF) >> 14;
        atomicAdd(&hist[ph * 256 + ((r >> 18) & 255)], 1);
    }
    __syncthreads();
    {   // thread t scans node t's 7 phase counts (conflict-free: stride 256)
        int acc = 0;
        for (int ph = 0; ph < NPH; ++ph) {
            int v = hist[ph * 256 + t];
            hist[ph * 256 + t] = acc;
            acc += v;
        }
        degsum[t] = acc;
    }
    __syncthreads();
    for (int i = lo + t; i < hi; i += 256) {
        unsigned r = binned[i];
        int sN = r & 0x1FFFF, g = (r >> 17) & 1, dlow = (r >> 18) & 255;
        int ph = sN >> 14;
        int p = atomicAdd(&hist[ph * 256 + dlow], 1);
        int dgv = g ? deg1[sN] : deg0[sN];
        es[rsl[dlow] + p] = sN | (g << 17) | (dgv << 18);
    }
    __syncthreads();
    if (n < NN) {
        int base = rsl[t], ds = degsum[t], dpv = (ds + 7) & ~7;
        for (int i = base + ds; i < base + dpv; ++i) es[i] = 0;
    }
}

// HA = fp16(x); BX = fp16(0.5*rD*x)
__global__ void convert_x(const float* __restrict__ X, const float* __restrict__ cy,
                          __half* __restrict__ HA, __half* __restrict__ BX) {
    int i = blockIdx.x * blockDim.x + threadIdx.x;
    if (i < NN * DIM / 4) {
        float4 v = ((const float4*)X)[i];
        float c = cy[i >> 4];
        ushort4 a, b;
        a.x = __half_as_ushort(__float2half(v.x));
        a.y = __half_as_ushort(__float2half(v.y));
        a.z = __half_as_ushort(__float2half(v.z));
        a.w = __half_as_ushort(__float2half(v.w));
        b.x = __half_as_ushort(__float2half(v.x * c));
        b.y = __half_as_ushort(__float2half(v.y * c));
        b.z = __half_as_ushort(__float2half(v.z * c));
        b.w = __half_as_ushort(__float2half(v.w * c));
        ((ushort4*)HA)[i] = a;
        ((ushort4*)BX)[i] = b;
    }
}

// One wave per node; fp16 state; packed 4B edge records; LDS rsqrt LUT.
__global__ void __launch_bounds__(256) step_kernel(
    const __half* __restrict__ Yh, const __half* __restrict__ BX,
    const int* __restrict__ rs, const int* __restrict__ dp,
    const int* __restrict__ es, const float2* __restrict__ nsc,
    const float* __restrict__ sc,
    __half* __restrict__ Yho, float* __restrict__ Ffo)
{
    __shared__ float lut[128];
    for (int i = threadIdx.x; i < 128; i += 256)
        lut[i] = (i == 0) ? 0.0f : rsqrtf((float)i);
    __syncthreads();

    int node = blockIdx.x * 4 + (threadIdx.x >> 6);  // NN % 4 == 0
    int d = threadIdx.x & 63;
    int un = __builtin_amdgcn_readfirstlane(node);
    int s  = __builtin_amdgcn_readfirstlane(rs[un]);
    int c  = __builtin_amdgcn_readfirstlane(dp[un]);
    float2 ns = nsc[un];

    float acc = 0.0f;
    int eb[8];
#pragma unroll
    for (int k = 0; k < 8; ++k) eb[k] = es[s + k];
    for (int i = 0; i < c; i += 8) {
        int en[8];
#pragma unroll
        for (int k = 0; k < 8; ++k) en[k] = es[s + i + 8 + k];  // slack-padded prefetch
        float yv[8];
#pragma unroll
        for (int k = 0; k < 8; ++k)
            yv[k] = __half2float(Yh[(size_t)(eb[k] & 0x1FFFF) * DIM + d]);
#pragma unroll
        for (int k = 0; k < 8; ++k) {
            float wsc = (eb[k] & (1 << 17)) ? ns.y : ns.x;
            acc = fmaf(yv[k], wsc * lut[eb[k] >> 18], acc);
        }
#pragma unroll
        for (int k = 0; k < 8; ++k) eb[k] = en[k];
    }
    float y  = __half2float(Yh[(size_t)un * DIM + d]);
    float bx = __half2float(BX[(size_t)un * DIM + d]);
    float o = fmaf(sc[un], y, bx) + acc;
    if (Ffo) Ffo[(size_t)un * DIM + d] = o;         // final step: f32 output
    else     Yho[(size_t)un * DIM + d] = __float2half(o);
}

extern "C" void kernel_launch(void* const* d_in, const int* in_sizes, int n_in,
                              void* d_out, int out_size, void* d_ws, size_t ws_size,
                              hipStream_t stream) {
    const float* x   = (const float*)d_in[0];
    const int* src0  = (const int*)d_in[1];
    const int* dst0  = (const int*)d_in[2];
    const int* src1  = (const int*)d_in[3];
    const int* dst1  = (const int*)d_in[4];
    float* out = (float*)d_out;

    char* ws = (char*)d_ws;
    size_t off = 0;
    auto alloc = [&](size_t bytes) -> void* {
        void* p = ws + off;
        off += (bytes + 255) & ~(size_t)255;
        return p;
    };

    const size_t ES_CAP = (size_t)2 * NE + 8 * NN + 64;  // padded CSR + prefetch slack

    __half* HA   = (__half*)alloc((size_t)NN * DIM * 2);
    __half* HB   = (__half*)alloc((size_t)NN * DIM * 2);
    __half* BX   = (__half*)alloc((size_t)NN * DIM * 2);
    unsigned int* binned = (unsigned int*)alloc((size_t)2 * NE * 4);
    int*    es   = (int*)alloc(ES_CAP * 4);
    int*    blk_cnt  = (int*)alloc((size_t)NBE * NBINS * 4);
    int*    blk_base = (int*)alloc((size_t)NBE * NBINS * 4);
    int*    bin_st   = (int*)alloc((size_t)(NBINS + 1) * 4);
    int*    deg0 = (int*)alloc((size_t)NN * 4);
    int*    deg1 = (int*)alloc((size_t)NN * 4);
    int*    rs   = (int*)alloc((size_t)NN * 4);
    int*    dp   = (int*)alloc((size_t)NN * 4);
    float2* nsc  = (float2*)alloc((size_t)NN * 8);
    float*  sc   = (float*)alloc((size_t)NN * 4);
    float*  cy   = (float*)alloc((size_t)NN * 4);
    int*    bs   = (int*)alloc((size_t)NBLK * 4);

    const int TB = 256;
    bin_count<<<NBE, 256, 0, stream>>>(dst0, dst1, blk_cnt);
    bin_scan<<<1, 512, 0, stream>>>(blk_cnt, bin_st);
    blk_base_k<<<NBINS, NBE, 0, stream>>>(blk_cnt, bin_st, blk_base);
    bin_permute<<<NBE, 256, 0, stream>>>(src0, dst0, src1, dst1, blk_base, binned);
    deg_count<<<NBINS, 256, 0, stream>>>(binned, bin_st, deg0, deg1);
    scan_l1<<<NBLK, 256, 0, stream>>>(deg0, deg1, rs, dp, bs);
    scan_l2<<<1, 512, 0, stream>>>(bs);
    scan_l3<<<NBLK, 256, 0, stream>>>(rs, bs);
    node_params<<<(NN + TB - 1) / TB, TB, 0, stream>>>(deg0, deg1, nsc, sc, cy);
    csr_scatter<<<NBINS, 256, 0, stream>>>(binned, bin_st, rs, deg0, deg1, es);
    convert_x<<<(NN * DIM / 4 + TB - 1) / TB, TB, 0, stream>>>(x, cy, HA, BX);

    int grid = NN / 4;
    for (int i = 0; i < 8; ++i) {
        const __half* hin = (i & 1) ? HB : HA;
        __half* hout = (i & 1) ? HA : HB;
        float* fout = (i == 7) ? out : nullptr;
        step_kernel<<<grid, TB, 0, stream>>>(hin, BX, rs, dp, es, nsc, sc, hout, fout);
    }
}

// Round 9
// 501.765 us; speedup vs baseline: 1.2130x; 1.0657x over previous
//
#include <hip/hip_runtime.h>
#include <hip/hip_fp16.h>

#define NN 100000
#define NE 1200000
#define DIM 64
#define NBINS 391                 // bin = dst >> 8  (256 nodes per bin)
#define NBE 128                   // edge-partition blocks
#define CHUNK (NE / NBE)          // 9375, exact
#define NBLK ((NN + 255) / 256)   // 391 scan blocks
#define NPH 7                     // src phases, phase = src >> 14

// out = sc[d]*y + bx[d] + sum_e w_e * Y[src_e]
//   sc = 0.5625 - 0.5*rD ; bx = 0.5*rD*x
//   g0 edge: w = (0.5*inv0[dst]) * rsqrt(deg0[src])
//   g1 edge: w = (-0.0625*inv1[dst]) * rsqrt(deg1[src])
// binned record (4B): [dstLow:8|g:1|src:17]   (dst = bin*256 + dstLow)
// es edge record (4B): [deg:7|g:1|src:17]

__global__ void __launch_bounds__(256) bin_count(const int* __restrict__ dst0,
                                                 const int* __restrict__ dst1,
                                                 int* __restrict__ blk_cnt) {
    __shared__ int c[NBINS];
    int t = threadIdx.x;
    for (int i = t; i < NBINS; i += 256) c[i] = 0;
    __syncthreads();
    int lo = blockIdx.x * CHUNK, hi = lo + CHUNK;
    for (int e = lo + t; e < hi; e += 256) {
        atomicAdd(&c[dst0[e] >> 8], 1);
        atomicAdd(&c[dst1[e] >> 8], 1);
    }
    __syncthreads();
    for (int i = t; i < NBINS; i += 256) blk_cnt[blockIdx.x * NBINS + i] = c[i];
}

__global__ void __launch_bounds__(512) bin_scan(const int* __restrict__ blk_cnt,
                                                int* __restrict__ bin_start) {
    __shared__ int tot[512];
    int t = threadIdx.x;
    int s = 0;
    if (t < NBINS)
        for (int b = 0; b < NBE; ++b) s += blk_cnt[b * NBINS + t];
    tot[t] = s;
    __syncthreads();
    for (int off = 1; off < 512; off <<= 1) {
        int v = (t >= off) ? tot[t - off] : 0;
        __syncthreads();
        tot[t] += v;
        __syncthreads();
    }
    if (t <= NBINS) bin_start[t] = tot[t] - s;
}

__global__ void __launch_bounds__(NBE) blk_base_k(const int* __restrict__ blk_cnt,
                                                  const int* __restrict__ bin_start,
                                                  int* __restrict__ blk_base) {
    __shared__ int s[NBE];
    int b = blockIdx.x, t = threadIdx.x;
    int v = blk_cnt[t * NBINS + b];
    s[t] = v;
    __syncthreads();
    for (int off = 1; off < NBE; off <<= 1) {
        int x = (t >= off) ? s[t - off] : 0;
        __syncthreads();
        s[t] += x;
        __syncthreads();
    }
    blk_base[t * NBINS + b] = bin_start[b] + s[t] - v;
}

__global__ void __launch_bounds__(256) bin_permute(const int* __restrict__ src0,
                                                   const int* __restrict__ dst0,
                                                   const int* __restrict__ src1,
                                                   const int* __restrict__ dst1,
                                                   const int* __restrict__ blk_base,
                                                   unsigned int* __restrict__ binned) {
    __shared__ int off[NBINS];
    int t = threadIdx.x;
    for (int i = t; i < NBINS; i += 256) off[i] = blk_base[blockIdx.x * NBINS + i];
    __syncthreads();
    int lo = blockIdx.x * CHUNK, hi = lo + CHUNK;
    for (int e = lo + t; e < hi; e += 256) {
        int s = src0[e], d = dst0[e];
        int p = atomicAdd(&off[d >> 8], 1);
        binned[p] = (unsigned)s | ((unsigned)(d & 255) << 18);
        s = src1[e]; d = dst1[e];
        p = atomicAdd(&off[d >> 8], 1);
        binned[p] = (unsigned)s | (1u << 17) | ((unsigned)(d & 255) << 18);
    }
}

__global__ void __launch_bounds__(256) deg_count(const unsigned int* __restrict__ binned,
                                                 const int* __restrict__ bin_start,
                                                 int* __restrict__ deg0,
                                                 int* __restrict__ deg1) {
    __shared__ int dg[512];
    int b = blockIdx.x, t = threadIdx.x;
    dg[t] = 0; dg[t + 256] = 0;
    __syncthreads();
    int lo = bin_start[b], hi = bin_start[b + 1];
    for (int i = lo + t; i < hi; i += 256) {
        unsigned r = binned[i];
        int dlow = (r >> 18) & 255, g = (r >> 17) & 1;
        atomicAdd(&dg[(dlow << 1) | g], 1);
    }
    __syncthreads();
    int n = b * 256 + t;
    if (n < NN) { deg0[n] = dg[t << 1]; deg1[n] = dg[(t << 1) | 1]; }
}

__global__ void __launch_bounds__(256) scan_l1(const int* __restrict__ deg0,
                                               const int* __restrict__ deg1,
                                               int* __restrict__ rs, int* __restrict__ dp,
                                               int* __restrict__ bs) {
    __shared__ int s0[256];
    int t = threadIdx.x;
    int n = blockIdx.x * 256 + t;
    int a = 0;
    if (n < NN) a = (deg0[n] + deg1[n] + 7) & ~7;
    s0[t] = a;
    __syncthreads();
    for (int off = 1; off < 256; off <<= 1) {
        int x0 = (t >= off) ? s0[t - off] : 0;
        __syncthreads();
        s0[t] += x0;
        __syncthreads();
    }
    if (n < NN) { rs[n] = s0[t] - a; dp[n] = a; }
    if (t == 255) bs[blockIdx.x] = s0[255];
}

__global__ void __launch_bounds__(512) scan_l2(int* __restrict__ bs) {
    __shared__ int s0[512];
    int t = threadIdx.x;
    int a = (t < NBLK) ? bs[t] : 0;
    s0[t] = a;
    __syncthreads();
    for (int off = 1; off < 512; off <<= 1) {
        int x0 = (t >= off) ? s0[t - off] : 0;
        __syncthreads();
        s0[t] += x0;
        __syncthreads();
    }
    if (t < NBLK) bs[t] = s0[t] - a;
}

__global__ void __launch_bounds__(256) scan_l3(int* __restrict__ rs, const int* __restrict__ bs) {
    int n = blockIdx.x * 256 + threadIdx.x;
    if (n < NN) rs[n] += bs[blockIdx.x];
}

__global__ void node_params(const int* __restrict__ deg0, const int* __restrict__ deg1,
                            float2* __restrict__ nsc, float* __restrict__ sc,
                            float* __restrict__ cy) {
    int n = blockIdx.x * blockDim.x + threadIdx.x;
    if (n < NN) {
        int a = deg0[n], b = deg1[n];
        nsc[n] = make_float2((a > 0) ? 0.5f * rsqrtf((float)a) : 0.0f,
                             (b > 0) ? -0.0625f * rsqrtf((float)b) : 0.0f);
        int s = a + b;
        float rD = (s > 0) ? 1.0f / (float)s : 0.0f;
        sc[n] = 0.5625f - 0.5f * rD;
        cy[n] = 0.5f * rD;
    }
}

// One block per bin, 2 passes: LDS (phase,node) histogram -> per-node scan
// -> phase-sorted scatter. Pad-fill folded in.
__global__ void __launch_bounds__(256) csr_scatter(const unsigned int* __restrict__ binned,
                                                   const int* __restrict__ bin_start,
                                                   const int* __restrict__ rs,
                                                   const int* __restrict__ deg0,
                                                   const int* __restrict__ deg1,
                                                   int* __restrict__ es) {
    __shared__ int hist[8 * 256];
    __shared__ int rsl[256];
    __shared__ int degsum[256];
    int b = blockIdx.x, t = threadIdx.x;
    int n = b * 256 + t;
    rsl[t] = (n < NN) ? rs[n] : 0;
    for (int i = t; i < 8 * 256; i += 256) hist[i] = 0;
    __syncthreads();
    int lo = bin_start[b], hi = bin_start[b + 1];
    for (int i = lo + t; i < hi; i += 256) {
        unsigned r = binned[i];
        int ph = (r & 0x1FFFF) >> 14;
        atomicAdd(&hist[ph * 256 + ((r >> 18) & 255)], 1);
    }
    __syncthreads();
    {
        int acc = 0;
        for (int ph = 0; ph < NPH; ++ph) {
            int v = hist[ph * 256 + t];
            hist[ph * 256 + t] = acc;
            acc += v;
        }
        degsum[t] = acc;
    }
    __syncthreads();
    for (int i = lo + t; i < hi; i += 256) {
        unsigned r = binned[i];
        int sN = r & 0x1FFFF, g = (r >> 17) & 1, dlow = (r >> 18) & 255;
        int ph = sN >> 14;
        int p = atomicAdd(&hist[ph * 256 + dlow], 1);
        int dgv = g ? deg1[sN] : deg0[sN];
        es[rsl[dlow] + p] = sN | (g << 17) | (dgv << 18);
    }
    __syncthreads();
    if (n < NN) {
        int base = rsl[t], ds = degsum[t], dpv = (ds + 7) & ~7;
        for (int i = base + ds; i < base + dpv; ++i) es[i] = 0;
    }
}

__global__ void convert_x(const float* __restrict__ X, const float* __restrict__ cy,
                          __half* __restrict__ HA, __half* __restrict__ BX) {
    int i = blockIdx.x * blockDim.x + threadIdx.x;
    if (i < NN * DIM / 4) {
        float4 v = ((const float4*)X)[i];
        float c = cy[i >> 4];
        ushort4 a, b;
        a.x = __half_as_ushort(__float2half(v.x));
        a.y = __half_as_ushort(__float2half(v.y));
        a.z = __half_as_ushort(__float2half(v.z));
        a.w = __half_as_ushort(__float2half(v.w));
        b.x = __half_as_ushort(__float2half(v.x * c));
        b.y = __half_as_ushort(__float2half(v.y * c));
        b.z = __half_as_ushort(__float2half(v.z * c));
        b.w = __half_as_ushort(__float2half(v.w * c));
        ((ushort4*)HA)[i] = a;
        ((ushort4*)BX)[i] = b;
    }
}

__device__ __forceinline__ float4 h4f(ushort4 v) {
    return make_float4(__half2float(__ushort_as_half(v.x)),
                       __half2float(__ushort_as_half(v.y)),
                       __half2float(__ushort_as_half(v.z)),
                       __half2float(__ushort_as_half(v.w)));
}

// One wave per node. Lane layout: sub = lane>>4 (edge slot), fl = lane&15
// (features 4fl..4fl+3, 8B ushort4 gathers). One gather instruction serves
// 4 edge rows (512B); records/decodes amortized 4x vs 1-feature-per-lane.
__global__ void __launch_bounds__(256) step_kernel(
    const __half* __restrict__ Yh, const __half* __restrict__ BX,
    const int* __restrict__ rs, const int* __restrict__ dp,
    const int* __restrict__ es, const float2* __restrict__ nsc,
    const float* __restrict__ sc,
    __half* __restrict__ Yho, float* __restrict__ Ffo)
{
    __shared__ float lut[128];
    for (int i = threadIdx.x; i < 128; i += 256)
        lut[i] = (i == 0) ? 0.0f : rsqrtf((float)i);
    __syncthreads();

    int node = blockIdx.x * 4 + (threadIdx.x >> 6);  // NN % 4 == 0
    int lane = threadIdx.x & 63;
    int sub  = lane >> 4;
    int fl   = lane & 15;
    int un = __builtin_amdgcn_readfirstlane(node);
    int s  = __builtin_amdgcn_readfirstlane(rs[un]);
    int c  = __builtin_amdgcn_readfirstlane(dp[un]);
    float2 ns = nsc[un];

    float4 acc = make_float4(0.0f, 0.0f, 0.0f, 0.0f);
    int r0 = es[s + sub];
    int r1 = es[s + 4 + sub];
    for (int i = 0; i < c; i += 8) {
        int n0 = es[s + i + 8 + sub];        // slack-padded prefetch
        int n1 = es[s + i + 12 + sub];
        ushort4 a0 = *(const ushort4*)(Yh + (size_t)(r0 & 0x1FFFF) * DIM + 4 * fl);
        ushort4 a1 = *(const ushort4*)(Yh + (size_t)(r1 & 0x1FFFF) * DIM + 4 * fl);
        float w0 = ((r0 & (1 << 17)) ? ns.y : ns.x) * lut[(unsigned)r0 >> 18];
        float w1 = ((r1 & (1 << 17)) ? ns.y : ns.x) * lut[(unsigned)r1 >> 18];
        float4 f0 = h4f(a0), f1 = h4f(a1);
        acc.x = fmaf(f0.x, w0, acc.x);
        acc.y = fmaf(f0.y, w0, acc.y);
        acc.z = fmaf(f0.z, w0, acc.z);
        acc.w = fmaf(f0.w, w0, acc.w);
        acc.x = fmaf(f1.x, w1, acc.x);
        acc.y = fmaf(f1.y, w1, acc.y);
        acc.z = fmaf(f1.z, w1, acc.z);
        acc.w = fmaf(f1.w, w1, acc.w);
        r0 = n0; r1 = n1;
    }
    // reduce the 4 edge slots (lanes fl, fl+16, fl+32, fl+48)
    acc.x += __shfl_xor(acc.x, 16); acc.x += __shfl_xor(acc.x, 32);
    acc.y += __shfl_xor(acc.y, 16); acc.y += __shfl_xor(acc.y, 32);
    acc.z += __shfl_xor(acc.z, 16); acc.z += __shfl_xor(acc.z, 32);
    acc.w += __shfl_xor(acc.w, 16); acc.w += __shfl_xor(acc.w, 32);

    if (sub == 0) {
        float4 y  = h4f(*(const ushort4*)(Yh + (size_t)un * DIM + 4 * fl));
        float4 bx = h4f(*(const ushort4*)(BX + (size_t)un * DIM + 4 * fl));
        float scl = sc[un];
        float o0 = fmaf(scl, y.x, bx.x) + acc.x;
        float o1 = fmaf(scl, y.y, bx.y) + acc.y;
        float o2 = fmaf(scl, y.z, bx.z) + acc.z;
        float o3 = fmaf(scl, y.w, bx.w) + acc.w;
        if (Ffo) {
            *(float4*)(Ffo + (size_t)un * DIM + 4 * fl) = make_float4(o0, o1, o2, o3);
        } else {
            ushort4 ov;
            ov.x = __half_as_ushort(__float2half(o0));
            ov.y = __half_as_ushort(__float2half(o1));
            ov.z = __half_as_ushort(__float2half(o2));
            ov.w = __half_as_ushort(__float2half(o3));
            *(ushort4*)(Yho + (size_t)un * DIM + 4 * fl) = ov;
        }
    }
}

extern "C" void kernel_launch(void* const* d_in, const int* in_sizes, int n_in,
                              void* d_out, int out_size, void* d_ws, size_t ws_size,
                              hipStream_t stream) {
    const float* x   = (const float*)d_in[0];
    const int* src0  = (const int*)d_in[1];
    const int* dst0  = (const int*)d_in[2];
    const int* src1  = (const int*)d_in[3];
    const int* dst1  = (const int*)d_in[4];
    float* out = (float*)d_out;

    char* ws = (char*)d_ws;
    size_t off = 0;
    auto alloc = [&](size_t bytes) -> void* {
        void* p = ws + off;
        off += (bytes + 255) & ~(size_t)255;
        return p;
    };

    const size_t ES_CAP = (size_t)2 * NE + 8 * NN + 64;  // padded CSR + prefetch slack

    __half* HA   = (__half*)alloc((size_t)NN * DIM * 2);
    __half* HB   = (__half*)alloc((size_t)NN * DIM * 2);
    __half* BX   = (__half*)alloc((size_t)NN * DIM * 2);
    unsigned int* binned = (unsigned int*)alloc((size_t)2 * NE * 4);
    int*    es   = (int*)alloc(ES_CAP * 4);
    int*    blk_cnt  = (int*)alloc((size_t)NBE * NBINS * 4);
    int*    blk_base = (int*)alloc((size_t)NBE * NBINS * 4);
    int*    bin_st   = (int*)alloc((size_t)(NBINS + 1) * 4);
    int*    deg0 = (int*)alloc((size_t)NN * 4);
    int*    deg1 = (int*)alloc((size_t)NN * 4);
    int*    rs   = (int*)alloc((size_t)NN * 4);
    int*    dp   = (int*)alloc((size_t)NN * 4);
    float2* nsc  = (float2*)alloc((size_t)NN * 8);
    float*  sc   = (float*)alloc((size_t)NN * 4);
    float*  cy   = (float*)alloc((size_t)NN * 4);
    int*    bs   = (int*)alloc((size_t)NBLK * 4);

    const int TB = 256;
    bin_count<<<NBE, 256, 0, stream>>>(dst0, dst1, blk_cnt);
    bin_scan<<<1, 512, 0, stream>>>(blk_cnt, bin_st);
    blk_base_k<<<NBINS, NBE, 0, stream>>>(blk_cnt, bin_st, blk_base);
    bin_permute<<<NBE, 256, 0, stream>>>(src0, dst0, src1, dst1, blk_base, binned);
    deg_count<<<NBINS, 256, 0, stream>>>(binned, bin_st, deg0, deg1);
    scan_l1<<<NBLK, 256, 0, stream>>>(deg0, deg1, rs, dp, bs);
    scan_l2<<<1, 512, 0, stream>>>(bs);
    scan_l3<<<NBLK, 256, 0, stream>>>(rs, bs);
    node_params<<<(NN + TB - 1) / TB, TB, 0, stream>>>(deg0, deg1, nsc, sc, cy);
    csr_scatter<<<NBINS, 256, 0, stream>>>(binned, bin_st, rs, deg0, deg1, es);
    convert_x<<<(NN * DIM / 4 + TB - 1) / TB, TB, 0, stream>>>(x, cy, HA, BX);

    int grid = NN / 4;
    for (int i = 0; i < 8; ++i) {
        const __half* hin = (i & 1) ? HB : HA;
        __half* hout = (i & 1) ? HA : HB;
        float* fout = (i == 7) ? out : nullptr;
        step_kernel<<<grid, TB, 0, stream>>>(hin, BX, rs, dp, es, nsc, sc, hout, fout);
    }
}

// Round 10
// 490.031 us; speedup vs baseline: 1.2420x; 1.0239x over previous
//
#include <hip/hip_runtime.h>
#include <hip/hip_fp16.h>

#define NN 100000
#define NE 1200000
#define DIM 64
#define NBINS 391                 // bin = dst >> 8  (256 nodes per bin)
#define NBE 128                   // edge-partition blocks
#define CHUNK (NE / NBE)          // 9375, exact
#define NBLK ((NN + 255) / 256)   // 391 scan blocks
#define NPH 7                     // src phases, phase = src >> 14

// out = sc[d]*y + bx[d] + sum_e w_e * Y[src_e]
//   sc = 0.5625 - 0.5*rD ; bx = 0.5*rD*x
//   w = nsc_g[dst] * rsqrt(deg_g[src]),  nsc = (+0.5*inv0, -0.0625*inv1)
// binned record (4B): [dstLow:8|g:1|src:17]   (dst = bin*256 + dstLow)
// es edge record (4B): [w_fp16_hi15:15|src:17]  (w LSB dropped, round-nearest)

__global__ void __launch_bounds__(256) bin_count(const int* __restrict__ dst0,
                                                 const int* __restrict__ dst1,
                                                 int* __restrict__ blk_cnt) {
    __shared__ int c[NBINS];
    int t = threadIdx.x;
    for (int i = t; i < NBINS; i += 256) c[i] = 0;
    __syncthreads();
    int lo = blockIdx.x * CHUNK, hi = lo + CHUNK;
    for (int e = lo + t; e < hi; e += 256) {
        atomicAdd(&c[dst0[e] >> 8], 1);
        atomicAdd(&c[dst1[e] >> 8], 1);
    }
    __syncthreads();
    for (int i = t; i < NBINS; i += 256) blk_cnt[blockIdx.x * NBINS + i] = c[i];
}

__global__ void __launch_bounds__(512) bin_scan(const int* __restrict__ blk_cnt,
                                                int* __restrict__ bin_start) {
    __shared__ int tot[512];
    int t = threadIdx.x;
    int s = 0;
    if (t < NBINS)
        for (int b = 0; b < NBE; ++b) s += blk_cnt[b * NBINS + t];
    tot[t] = s;
    __syncthreads();
    for (int off = 1; off < 512; off <<= 1) {
        int v = (t >= off) ? tot[t - off] : 0;
        __syncthreads();
        tot[t] += v;
        __syncthreads();
    }
    if (t <= NBINS) bin_start[t] = tot[t] - s;
}

__global__ void __launch_bounds__(NBE) blk_base_k(const int* __restrict__ blk_cnt,
                                                  const int* __restrict__ bin_start,
                                                  int* __restrict__ blk_base) {
    __shared__ int s[NBE];
    int b = blockIdx.x, t = threadIdx.x;
    int v = blk_cnt[t * NBINS + b];
    s[t] = v;
    __syncthreads();
    for (int off = 1; off < NBE; off <<= 1) {
        int x = (t >= off) ? s[t - off] : 0;
        __syncthreads();
        s[t] += x;
        __syncthreads();
    }
    blk_base[t * NBINS + b] = bin_start[b] + s[t] - v;
}

__global__ void __launch_bounds__(256) bin_permute(const int* __restrict__ src0,
                                                   const int* __restrict__ dst0,
                                                   const int* __restrict__ src1,
                                                   const int* __restrict__ dst1,
                                                   const int* __restrict__ blk_base,
                                                   unsigned int* __restrict__ binned) {
    __shared__ int off[NBINS];
    int t = threadIdx.x;
    for (int i = t; i < NBINS; i += 256) off[i] = blk_base[blockIdx.x * NBINS + i];
    __syncthreads();
    int lo = blockIdx.x * CHUNK, hi = lo + CHUNK;
    for (int e = lo + t; e < hi; e += 256) {
        int s = src0[e], d = dst0[e];
        int p = atomicAdd(&off[d >> 8], 1);
        binned[p] = (unsigned)s | ((unsigned)(d & 255) << 18);
        s = src1[e]; d = dst1[e];
        p = atomicAdd(&off[d >> 8], 1);
        binned[p] = (unsigned)s | (1u << 17) | ((unsigned)(d & 255) << 18);
    }
}

__global__ void __launch_bounds__(256) deg_count(const unsigned int* __restrict__ binned,
                                                 const int* __restrict__ bin_start,
                                                 int* __restrict__ deg0,
                                                 int* __restrict__ deg1) {
    __shared__ int dg[512];
    int b = blockIdx.x, t = threadIdx.x;
    dg[t] = 0; dg[t + 256] = 0;
    __syncthreads();
    int lo = bin_start[b], hi = bin_start[b + 1];
    for (int i = lo + t; i < hi; i += 256) {
        unsigned r = binned[i];
        int dlow = (r >> 18) & 255, g = (r >> 17) & 1;
        atomicAdd(&dg[(dlow << 1) | g], 1);
    }
    __syncthreads();
    int n = b * 256 + t;
    if (n < NN) { deg0[n] = dg[t << 1]; deg1[n] = dg[(t << 1) | 1]; }
}

__global__ void __launch_bounds__(256) scan_l1(const int* __restrict__ deg0,
                                               const int* __restrict__ deg1,
                                               int* __restrict__ rs, int* __restrict__ dp,
                                               int* __restrict__ bs) {
    __shared__ int s0[256];
    int t = threadIdx.x;
    int n = blockIdx.x * 256 + t;
    int a = 0;
    if (n < NN) a = (deg0[n] + deg1[n] + 7) & ~7;
    s0[t] = a;
    __syncthreads();
    for (int off = 1; off < 256; off <<= 1) {
        int x0 = (t >= off) ? s0[t - off] : 0;
        __syncthreads();
        s0[t] += x0;
        __syncthreads();
    }
    if (n < NN) { rs[n] = s0[t] - a; dp[n] = a; }
    if (t == 255) bs[blockIdx.x] = s0[255];
}

__global__ void __launch_bounds__(512) scan_l2(int* __restrict__ bs) {
    __shared__ int s0[512];
    int t = threadIdx.x;
    int a = (t < NBLK) ? bs[t] : 0;
    s0[t] = a;
    __syncthreads();
    for (int off = 1; off < 512; off <<= 1) {
        int x0 = (t >= off) ? s0[t - off] : 0;
        __syncthreads();
        s0[t] += x0;
        __syncthreads();
    }
    if (t < NBLK) bs[t] = s0[t] - a;
}

__global__ void __launch_bounds__(256) scan_l3(int* __restrict__ rs, const int* __restrict__ bs) {
    int n = blockIdx.x * 256 + threadIdx.x;
    if (n < NN) rs[n] += bs[blockIdx.x];
}

__global__ void node_params(const int* __restrict__ deg0, const int* __restrict__ deg1,
                            float2* __restrict__ nsc, float* __restrict__ sc,
                            float* __restrict__ cy) {
    int n = blockIdx.x * blockDim.x + threadIdx.x;
    if (n < NN) {
        int a = deg0[n], b = deg1[n];
        nsc[n] = make_float2((a > 0) ? 0.5f * rsqrtf((float)a) : 0.0f,
                             (b > 0) ? -0.0625f * rsqrtf((float)b) : 0.0f);
        int s = a + b;
        float rD = (s > 0) ? 1.0f / (float)s : 0.0f;
        sc[n] = 0.5625f - 0.5f * rD;
        cy[n] = 0.5f * rD;
    }
}

// One block per bin, 2 passes: LDS (phase,node) histogram -> per-node scan ->
// phase-sorted scatter with pre-folded fp15 weights. Pad-fill folded in.
__global__ void __launch_bounds__(256) csr_scatter(const unsigned int* __restrict__ binned,
                                                   const int* __restrict__ bin_start,
                                                   const int* __restrict__ rs,
                                                   const int* __restrict__ deg0,
                                                   const int* __restrict__ deg1,
                                                   const float2* __restrict__ nsc,
                                                   int* __restrict__ es) {
    __shared__ int hist[8 * 256];
    __shared__ int rsl[256];
    __shared__ int degsum[256];
    __shared__ float2 nscl[256];
    int b = blockIdx.x, t = threadIdx.x;
    int n = b * 256 + t;
    rsl[t]  = (n < NN) ? rs[n] : 0;
    nscl[t] = (n < NN) ? nsc[n] : make_float2(0.0f, 0.0f);
    for (int i = t; i < 8 * 256; i += 256) hist[i] = 0;
    __syncthreads();
    int lo = bin_start[b], hi = bin_start[b + 1];
    for (int i = lo + t; i < hi; i += 256) {
        unsigned r = binned[i];
        int ph = (r & 0x1FFFF) >> 14;
        atomicAdd(&hist[ph * 256 + ((r >> 18) & 255)], 1);
    }
    __syncthreads();
    {
        int acc = 0;
        for (int ph = 0; ph < NPH; ++ph) {
            int v = hist[ph * 256 + t];
            hist[ph * 256 + t] = acc;
            acc += v;
        }
        degsum[t] = acc;
    }
    __syncthreads();
    for (int i = lo + t; i < hi; i += 256) {
        unsigned r = binned[i];
        int sN = r & 0x1FFFF, g = (r >> 17) & 1, dlow = (r >> 18) & 255;
        int ph = sN >> 14;
        int p = atomicAdd(&hist[ph * 256 + dlow], 1);
        int dgv = g ? deg1[sN] : deg0[sN];
        float2 nn = nscl[dlow];
        float wf = (g ? nn.y : nn.x) * rsqrtf((float)dgv);
        unsigned u = (unsigned)__half_as_ushort(__float2half(wf));
        es[rsl[dlow] + p] = (int)((((u + 1u) >> 1) << 17) | (unsigned)sN);
    }
    __syncthreads();
    if (n < NN) {
        int base = rsl[t], ds = degsum[t], dpv = (ds + 7) & ~7;
        for (int i = base + ds; i < base + dpv; ++i) es[i] = 0;  // w=+0, src=0
    }
}

__global__ void convert_x(const float* __restrict__ X, const float* __restrict__ cy,
                          __half* __restrict__ HA, __half* __restrict__ BX) {
    int i = blockIdx.x * blockDim.x + threadIdx.x;
    if (i < NN * DIM / 4) {
        float4 v = ((const float4*)X)[i];
        float c = cy[i >> 4];
        ushort4 a, b;
        a.x = __half_as_ushort(__float2half(v.x));
        a.y = __half_as_ushort(__float2half(v.y));
        a.z = __half_as_ushort(__float2half(v.z));
        a.w = __half_as_ushort(__float2half(v.w));
        b.x = __half_as_ushort(__float2half(v.x * c));
        b.y = __half_as_ushort(__float2half(v.y * c));
        b.z = __half_as_ushort(__float2half(v.z * c));
        b.w = __half_as_ushort(__float2half(v.w * c));
        ((ushort4*)HA)[i] = a;
        ((ushort4*)BX)[i] = b;
    }
}

__device__ __forceinline__ float4 h4f(ushort4 v) {
    return make_float4(__half2float(__ushort_as_half(v.x)),
                       __half2float(__ushort_as_half(v.y)),
                       __half2float(__ushort_as_half(v.z)),
                       __half2float(__ushort_as_half(v.w)));
}

__device__ __forceinline__ float wdec(int r) {
    return __half2float(__ushort_as_half((unsigned short)(((unsigned)r >> 16) & 0xFFFEu)));
}

// One wave per node. sub = lane>>4 (record-pair slot), fl = lane&15 (features
// 4fl..4fl+3). 2-deep pipeline: records fetched 2 batches ahead (int2 pair),
// gathers issued 1 batch ahead -> 4 row-gathers in flight per wave.
__global__ void __launch_bounds__(256) step_kernel(
    const __half* __restrict__ Yh, const __half* __restrict__ BX,
    const int* __restrict__ rs, const int* __restrict__ dp,
    const int* __restrict__ es, const float* __restrict__ sc,
    __half* __restrict__ Yho, float* __restrict__ Ffo)
{
    int node = blockIdx.x * 4 + (threadIdx.x >> 6);  // NN % 4 == 0
    int lane = threadIdx.x & 63;
    int sub  = lane >> 4;
    int fl   = lane & 15;
    int un = __builtin_amdgcn_readfirstlane(node);
    int s  = __builtin_amdgcn_readfirstlane(rs[un]);
    int c  = __builtin_amdgcn_readfirstlane(dp[un]);

    const int2* ep = (const int2*)(es + s) + sub;  // ep[j] = records (s+2*(sub+j))

    float4 acc = make_float4(0.0f, 0.0f, 0.0f, 0.0f);
    int2 rA = ep[0];   // batch 0 pair for this slot
    int2 rB = ep[4];   // batch 1
    ushort4 gA0 = *(const ushort4*)(Yh + (size_t)(rA.x & 0x1FFFF) * DIM + 4 * fl);
    ushort4 gA1 = *(const ushort4*)(Yh + (size_t)(rA.y & 0x1FFFF) * DIM + 4 * fl);
    for (int i = 0; i < c; i += 8) {
        int2 rC = ep[(i >> 1) + 8];  // batch i/8 + 2 (slack-covered)
        ushort4 gB0 = *(const ushort4*)(Yh + (size_t)(rB.x & 0x1FFFF) * DIM + 4 * fl);
        ushort4 gB1 = *(const ushort4*)(Yh + (size_t)(rB.y & 0x1FFFF) * DIM + 4 * fl);
        float w0 = wdec(rA.x);
        float w1 = wdec(rA.y);
        float4 f0 = h4f(gA0), f1 = h4f(gA1);
        acc.x = fmaf(f0.x, w0, acc.x);
        acc.y = fmaf(f0.y, w0, acc.y);
        acc.z = fmaf(f0.z, w0, acc.z);
        acc.w = fmaf(f0.w, w0, acc.w);
        acc.x = fmaf(f1.x, w1, acc.x);
        acc.y = fmaf(f1.y, w1, acc.y);
        acc.z = fmaf(f1.z, w1, acc.z);
        acc.w = fmaf(f1.w, w1, acc.w);
        rA = rB; rB = rC; gA0 = gB0; gA1 = gB1;
    }
    // reduce the 4 record slots (lanes fl, fl+16, fl+32, fl+48)
    acc.x += __shfl_xor(acc.x, 16); acc.x += __shfl_xor(acc.x, 32);
    acc.y += __shfl_xor(acc.y, 16); acc.y += __shfl_xor(acc.y, 32);
    acc.z += __shfl_xor(acc.z, 16); acc.z += __shfl_xor(acc.z, 32);
    acc.w += __shfl_xor(acc.w, 16); acc.w += __shfl_xor(acc.w, 32);

    if (sub == 0) {
        float4 y  = h4f(*(const ushort4*)(Yh + (size_t)un * DIM + 4 * fl));
        float4 bx = h4f(*(const ushort4*)(BX + (size_t)un * DIM + 4 * fl));
        float scl = sc[un];
        float o0 = fmaf(scl, y.x, bx.x) + acc.x;
        float o1 = fmaf(scl, y.y, bx.y) + acc.y;
        float o2 = fmaf(scl, y.z, bx.z) + acc.z;
        float o3 = fmaf(scl, y.w, bx.w) + acc.w;
        if (Ffo) {
            *(float4*)(Ffo + (size_t)un * DIM + 4 * fl) = make_float4(o0, o1, o2, o3);
        } else {
            ushort4 ov;
            ov.x = __half_as_ushort(__float2half(o0));
            ov.y = __half_as_ushort(__float2half(o1));
            ov.z = __half_as_ushort(__float2half(o2));
            ov.w = __half_as_ushort(__float2half(o3));
            *(ushort4*)(Yho + (size_t)un * DIM + 4 * fl) = ov;
        }
    }
}

extern "C" void kernel_launch(void* const* d_in, const int* in_sizes, int n_in,
                              void* d_out, int out_size, void* d_ws, size_t ws_size,
                              hipStream_t stream) {
    const float* x   = (const float*)d_in[0];
    const int* src0  = (const int*)d_in[1];
    const int* dst0  = (const int*)d_in[2];
    const int* src1  = (const int*)d_in[3];
    const int* dst1  = (const int*)d_in[4];
    float* out = (float*)d_out;

    char* ws = (char*)d_ws;
    size_t off = 0;
    auto alloc = [&](size_t bytes) -> void* {
        void* p = ws + off;
        off += (bytes + 255) & ~(size_t)255;
        return p;
    };

    const size_t ES_CAP = (size_t)2 * NE + 8 * NN + 128;  // padded CSR + pipeline slack

    __half* HA   = (__half*)alloc((size_t)NN * DIM * 2);
    __half* HB   = (__half*)alloc((size_t)NN * DIM * 2);
    __half* BX   = (__half*)alloc((size_t)NN * DIM * 2);
    unsigned int* binned = (unsigned int*)alloc((size_t)2 * NE * 4);
    int*    es   = (int*)alloc(ES_CAP * 4);
    int*    blk_cnt  = (int*)alloc((size_t)NBE * NBINS * 4);
    int*    blk_base = (int*)alloc((size_t)NBE * NBINS * 4);
    int*    bin_st   = (int*)alloc((size_t)(NBINS + 1) * 4);
    int*    deg0 = (int*)alloc((size_t)NN * 4);
    int*    deg1 = (int*)alloc((size_t)NN * 4);
    int*    rs   = (int*)alloc((size_t)NN * 4);
    int*    dp   = (int*)alloc((size_t)NN * 4);
    float2* nsc  = (float2*)alloc((size_t)NN * 8);
    float*  sc   = (float*)alloc((size_t)NN * 4);
    float*  cy   = (float*)alloc((size_t)NN * 4);
    int*    bs   = (int*)alloc((size_t)NBLK * 4);

    const int TB = 256;
    bin_count<<<NBE, 256, 0, stream>>>(dst0, dst1, blk_cnt);
    bin_scan<<<1, 512, 0, stream>>>(blk_cnt, bin_st);
    blk_base_k<<<NBINS, NBE, 0, stream>>>(blk_cnt, bin_st, blk_base);
    bin_permute<<<NBE, 256, 0, stream>>>(src0, dst0, src1, dst1, blk_base, binned);
    deg_count<<<NBINS, 256, 0, stream>>>(binned, bin_st, deg0, deg1);
    scan_l1<<<NBLK, 256, 0, stream>>>(deg0, deg1, rs, dp, bs);
    scan_l2<<<1, 512, 0, stream>>>(bs);
    scan_l3<<<NBLK, 256, 0, stream>>>(rs, bs);
    node_params<<<(NN + TB - 1) / TB, TB, 0, stream>>>(deg0, deg1, nsc, sc, cy);
    csr_scatter<<<NBINS, 256, 0, stream>>>(binned, bin_st, rs, deg0, deg1, nsc, es);
    convert_x<<<(NN * DIM / 4 + TB - 1) / TB, TB, 0, stream>>>(x, cy, HA, BX);

    int grid = NN / 4;
    for (int i = 0; i < 8; ++i) {
        const __half* hin = (i & 1) ? HB : HA;
        __half* hout = (i & 1) ? HA : HB;
        float* fout = (i == 7) ? out : nullptr;
        step_kernel<<<grid, TB, 0, stream>>>(hin, BX, rs, dp, es, sc, hout, fout);
    }
}